// Round 1
// baseline (1574.619 us; speedup 1.0000x reference)
//
#include <hip/hip_runtime.h>
#include <stdint.h>

#define BB 8
#define CCH 64
#define NPB 4096
#define KK 16
#define NPTS (BB*NPB)   // 32768

typedef float vf16 __attribute__((ext_vector_type(16)));

// ---------------- K1: transpose x (B,C,N) -> xb (B,N,C) ----------------
__global__ void k_transpose(const float* __restrict__ x, float* __restrict__ xb) {
    __shared__ float tile[64][65];
    int b  = blockIdx.y;
    int n0 = blockIdx.x * 64;
    int tx = threadIdx.x, ty = threadIdx.y;   // 64 x 8
    const float* xp = x + (size_t)b * CCH * NPB;
#pragma unroll
    for (int r = 0; r < 8; ++r) {
        int c = ty + r * 8;
        tile[c][tx] = xp[(size_t)c * NPB + n0 + tx];
    }
    __syncthreads();
    float* xbp = xb + ((size_t)b * NPB + n0) * CCH;
#pragma unroll
    for (int r = 0; r < 8; ++r) {
        int nn = ty + r * 8;
        xbp[(size_t)nn * CCH + tx] = tile[tx][nn];
    }
}

// ---------------- K1b: per-point sum of squares ----------------
__global__ void k_sq(const float* __restrict__ xb, float* __restrict__ sq) {
    int p = blockIdx.x * 256 + threadIdx.x;
    const float4* r = (const float4*)(xb + (size_t)p * CCH);
    float s = 0.0f;
#pragma unroll
    for (int i = 0; i < 16; ++i) {
        float4 v = r[i];
        s += v.x * v.x + v.y * v.y + v.z * v.z + v.w * v.w;
    }
    sq[p] = s;
}

// ---------------- K2: distances + per-(row,colsplit) top-16 ----------------
// block = 512 threads (one row each); grid = (4 col-splits, 64 row-blocks)
// key = (monotonic_bits(sq[col] - 2*dot) << 32) | col   -> lex (d asc, idx asc)
__global__ __launch_bounds__(512, 2) void k_knn(const float* __restrict__ xb,
                                                const float* __restrict__ sq,
                                                unsigned long long* __restrict__ cand) {
    int tid  = threadIdx.x;
    int row  = blockIdx.y * 512 + tid;          // global point
    int b    = row >> 12;
    int split = blockIdx.x;
    const float* xbB = xb + ((size_t)(b) << 12) * CCH;
    const float* sqB = sq + ((size_t)(b) << 12);

    // my row's features -> registers
    float rr[CCH];
    {
        const float4* rp = (const float4*)(xbB + (size_t)(row & 4095) * CCH);
#pragma unroll
        for (int i = 0; i < 16; ++i) {
            float4 v = rp[i];
            rr[4*i] = v.x; rr[4*i+1] = v.y; rr[4*i+2] = v.z; rr[4*i+3] = v.w;
        }
    }

    unsigned long long list[16];
#pragma unroll
    for (int s = 0; s < 16; ++s) list[s] = ~0ULL;

    int colBase = split * 1024;
    for (int t = 0; t < 16; ++t) {              // 16 tiles of 64 cols
        int c0 = colBase + t * 64;
        float d[64];
        // ---- compute d[cc] = sq[col] - 2*dot(row,col), cols uniform -> s_load ----
#pragma unroll
        for (int cc = 0; cc < 64; cc += 2) {
            float a0 = 0.f, a1 = 0.f;
            const float* col0 = xbB + (size_t)(c0 + cc) * CCH;
            const float* col1 = xbB + (size_t)(c0 + cc + 1) * CCH;
#pragma unroll
            for (int q = 0; q < 4; ++q) {
                vf16 v0 = *(const vf16*)(col0 + q * 16);
                vf16 v1 = *(const vf16*)(col1 + q * 16);
#pragma unroll
                for (int e = 0; e < 16; ++e) {
                    a0 = fmaf(v0[e], rr[q * 16 + e], a0);
                    a1 = fmaf(v1[e], rr[q * 16 + e], a1);
                }
            }
            d[cc]     = fmaf(-2.f, a0, sqB[c0 + cc]);
            d[cc + 1] = fmaf(-2.f, a1, sqB[c0 + cc + 1]);
        }
        // ---- selection rounds: extract tile-min, insert into sorted-16 ----
        while (true) {
            float mv = d[0]; int ms = 0;
#pragma unroll
            for (int s = 1; s < 64; ++s) {
                bool lt = d[s] < mv;            // strict: keeps lowest col on ties
                mv = lt ? d[s] : mv;
                ms = lt ? s : ms;
            }
            unsigned int fb = __float_as_uint(mv);
            fb ^= (fb >> 31) ? 0xFFFFFFFFu : 0x80000000u;   // monotonic transform
            unsigned long long key =
                ((unsigned long long)fb << 32) | (unsigned int)(c0 + ms);
            bool want = key < list[15];
            if (!__any(want)) break;
            if (want) {
                bool bs[16];
#pragma unroll
                for (int s = 0; s < 16; ++s) bs[s] = key < list[s];
#pragma unroll
                for (int s = 15; s >= 1; --s)
                    list[s] = bs[s] ? (bs[s - 1] ? list[s - 1] : key) : list[s];
                list[0] = bs[0] ? key : list[0];
#pragma unroll
                for (int s = 0; s < 64; ++s)
                    if (s == ms) d[s] = __builtin_inff();
            }
        }
    }
    unsigned long long* cp = cand + (((size_t)row * 4) + split) * 16;
#pragma unroll
    for (int s = 0; s < 16; ++s) cp[s] = list[s];
}

// ---------------- K3: merge 4 sorted 16-lists -> final idx[16] ----------------
__global__ void k_merge(const unsigned long long* __restrict__ cand,
                        int* __restrict__ idxo) {
    int row = blockIdx.x * 256 + threadIdx.x;
    const unsigned long long* cp = cand + (size_t)row * 64;
    int p0 = 0, p1 = 0, p2 = 0, p3 = 0;
    for (int k = 0; k < 16; ++k) {
        unsigned long long v0 = cp[p0];
        unsigned long long v1 = cp[16 + p1];
        unsigned long long v2 = cp[32 + p2];
        unsigned long long v3 = cp[48 + p3];
        unsigned long long m = v0; int w = 0;
        if (v1 < m) { m = v1; w = 1; }
        if (v2 < m) { m = v2; w = 2; }
        if (v3 < m) { m = v3; w = 3; }
        if (w == 0) p0++; else if (w == 1) p1++; else if (w == 2) p2++; else p3++;
        idxo[(size_t)row * 16 + k] = (int)(m & 0xFFFFFFFFu);
    }
}

// ---------------- K4: fused edge-MLP + max over K ----------------
// lane = output channel o. W1 folded: h1 = relu(b1 + xi@(W1a-W1b) + xj@W1b)
// layer2 via readlane broadcast of h1 across the wave. W's register-resident.
__global__ __launch_bounds__(256, 2) void k_mlp(const float* __restrict__ xb,
                                                const int* __restrict__ idx,
                                                const float* __restrict__ W1,
                                                const float* __restrict__ b1,
                                                const float* __restrict__ W2,
                                                const float* __restrict__ b2,
                                                float* __restrict__ out) {
    int lane = threadIdx.x & 63;
    int wave = (blockIdx.x * 256 + threadIdx.x) >> 6;   // 0..2047
    int o = lane;
    float wa[64], wb[64], w2r[64];
#pragma unroll
    for (int c = 0; c < 64; ++c) {
        float w1a = W1[c * 64 + o];
        float w1b = W1[(64 + c) * 64 + o];
        wa[c] = w1a - w1b;
        wb[c] = w1b;
        w2r[c] = W2[c * 64 + o];
    }
    float bb1 = b1[o], bb2 = b2[o];
    int p0 = wave * 16;
    for (int pi = 0; pi < 16; ++pi) {
        int p = p0 + pi;
        int b = p >> 12;
        int n = p & 4095;
        const float* xbB = xb + ((size_t)b << 12) * CCH;
        const float* xi = xbB + (size_t)n * CCH;
        float pre = bb1;
#pragma unroll
        for (int c4 = 0; c4 < 16; ++c4) {
            float4 v = *(const float4*)(xi + c4 * 4);
            pre = fmaf(v.x, wa[c4 * 4 + 0], pre);
            pre = fmaf(v.y, wa[c4 * 4 + 1], pre);
            pre = fmaf(v.z, wa[c4 * 4 + 2], pre);
            pre = fmaf(v.w, wa[c4 * 4 + 3], pre);
        }
        const int* ip = idx + (size_t)p * 16;
        float mx = 0.f;
        for (int k = 0; k < 16; ++k) {
            int j = ip[k];                              // uniform
            const float* xj = xbB + (size_t)j * CCH;
            float h = pre;
#pragma unroll
            for (int c4 = 0; c4 < 16; ++c4) {
                float4 v = *(const float4*)(xj + c4 * 4);
                h = fmaf(v.x, wb[c4 * 4 + 0], h);
                h = fmaf(v.y, wb[c4 * 4 + 1], h);
                h = fmaf(v.z, wb[c4 * 4 + 2], h);
                h = fmaf(v.w, wb[c4 * 4 + 3], h);
            }
            float h1 = fmaxf(h, 0.f);
            float acc = bb2;
#pragma unroll
            for (int j2 = 0; j2 < 64; ++j2) {
                float hj = __int_as_float(
                    __builtin_amdgcn_readlane(__float_as_int(h1), j2));
                acc = fmaf(hj, w2r[j2], acc);
            }
            float h2 = fmaxf(acc, 0.f);
            mx = fmaxf(mx, h2);
        }
        out[((size_t)b * 64 + o) * NPB + n] = mx;
    }
}

extern "C" void kernel_launch(void* const* d_in, const int* in_sizes, int n_in,
                              void* d_out, int out_size, void* d_ws, size_t ws_size,
                              hipStream_t stream) {
    const float* x  = (const float*)d_in[0];
    const float* W1 = (const float*)d_in[1];
    const float* b1 = (const float*)d_in[2];
    const float* W2 = (const float*)d_in[3];
    const float* b2 = (const float*)d_in[4];
    float* out = (float*)d_out;

    char* ws = (char*)d_ws;
    float* xb = (float*)ws;                                             // 8 MB
    float* sq = (float*)(ws + (size_t)8 * 1024 * 1024);                 // 128 KB
    unsigned long long* cand =
        (unsigned long long*)(ws + (size_t)9 * 1024 * 1024);            // 16 MB
    int* idxb = (int*)(ws + (size_t)25 * 1024 * 1024);                  // 2 MB

    hipLaunchKernelGGL(k_transpose, dim3(NPB / 64, BB), dim3(64, 8), 0, stream, x, xb);
    hipLaunchKernelGGL(k_sq, dim3(NPTS / 256), dim3(256), 0, stream, xb, sq);
    hipLaunchKernelGGL(k_knn, dim3(4, NPTS / 512), dim3(512), 0, stream, xb, sq, cand);
    hipLaunchKernelGGL(k_merge, dim3(NPTS / 256), dim3(256), 0, stream, cand, idxb);
    hipLaunchKernelGGL(k_mlp, dim3(512), dim3(256), 0, stream, xb, idxb, W1, b1, W2, b2, out);
}